// Round 1
// 249.061 us; speedup vs baseline: 1.0289x; 1.0289x over previous
//
#include <hip/hip_runtime.h>

#define N_NODES 50000
#define N_EDGES 800000
#define F 128
#define BF 256
#define NF (N_NODES * F)
#define CAP 64                       // slots per node (max degree here ~40)
#define SPILL_CAP 131072
#define PRE_BLOCKS 3200
#define PRE_THREADS (PRE_BLOCKS * 256)

typedef __attribute__((ext_vector_type(8))) _Float16 half8;
typedef __attribute__((ext_vector_type(4))) _Float16 half4;
typedef __attribute__((ext_vector_type(4))) float floatx4;

#define RL_I(v, l) __builtin_amdgcn_readlane((v), (l))

// ========== build: one pass — slot-scatter edges + x -> fp16 interleaved ====
__global__ __launch_bounds__(256) void k_build(const int* __restrict__ ei,
                                               const float* __restrict__ attr,
                                               const float* __restrict__ x,
                                               int* __restrict__ cnt,       // [N+1], last = nspill
                                               uint4* __restrict__ spill,
                                               uint2* __restrict__ slots,   // [N][CAP]
                                               _Float16* __restrict__ xi) {
    int t = blockIdx.x * 256 + threadIdx.x;
    if (t < N_EDGES) {
        int r = ei[t];
        int c = ei[N_EDGES + t];
        float a = attr[t];
        int slot = atomicAdd(&cnt[r], 1);
        if (slot < CAP) {
            slots[(size_t)r * CAP + slot] = make_uint2((unsigned)c, __float_as_uint(a));
        } else {
            int sp = atomicAdd(&cnt[N_NODES], 1);
            if (sp < SPILL_CAP)
                spill[sp] = make_uint4((unsigned)r, (unsigned)c, __float_as_uint(a), 0u);
        }
    }
    // fused cvt: x[b][n][f] fp32 -> xi[n][b*128+f] fp16
    for (int i = t; i < 2 * NF / 4; i += PRE_THREADS) {
        size_t base = (size_t)i * 4;
        int b = (base >= (size_t)NF) ? 1 : 0;
        size_t rem = base - (size_t)b * NF;
        int n = (int)(rem >> 7);
        int f = (int)(rem & 127);
        float4 v = *(const float4*)(x + base);
        half4 h;
        h[0] = (_Float16)v.x; h[1] = (_Float16)v.y;
        h[2] = (_Float16)v.z; h[3] = (_Float16)v.w;
        *(half4*)(xi + (size_t)n * BF + b * F + f) = h;
    }
}

// ========== dinv[r] = rsqrt(1 + sum attr): one wave per row ================
__global__ __launch_bounds__(256) void k_deg_s(const int* __restrict__ cnt,
                                               const uint2* __restrict__ slots,
                                               const uint4* __restrict__ spill,
                                               float* __restrict__ dinv) {
    int r    = (int)(((size_t)blockIdx.x * 256 + threadIdx.x) >> 6);
    int lane = threadIdx.x & 63;
    if (r >= N_NODES) return;
    int cn = cnt[r];
    int m  = (cn < CAP) ? cn : CAP;
    float a = 0.0f;
    if (lane < m) a = __uint_as_float(slots[(size_t)r * CAP + lane].y);
    if (cn > CAP) {                       // spilled rows only
        int ns = cnt[N_NODES]; if (ns > SPILL_CAP) ns = SPILL_CAP;
        for (int i = lane; i < ns; i += 64) {
            uint4 e = spill[i];
            if ((int)e.x == r) a += __uint_as_float(e.z);
        }
    }
    for (int off = 32; off > 0; off >>= 1) a += __shfl_down(a, off);
    if (lane == 0) dinv[r] = rsqrtf(a + 1.0f);
}

// Unrolled neighbor accumulation: 8 independent wave-wide 512B loads in
// flight (SGPR base addressing via readlane), then a 4-tail, then singles.
// This is the latency-hiding fix: previous code held ~1 load outstanding.
#define NB_ONE(CJ, PJ)                                                        \
    {                                                                         \
        half4 v = *(const half4*)(xi + (size_t)(CJ) * BF + idx);              \
        acc.x += (PJ) * (float)v[0]; acc.y += (PJ) * (float)v[1];             \
        acc.z += (PJ) * (float)v[2]; acc.w += (PJ) * (float)v[3];             \
        sp += (PJ);                                                           \
    }

#define NB_BODY                                                               \
    float4 acc  = make_float4(0.f, 0.f, 0.f, 0.f);                            \
    float4 accB = make_float4(0.f, 0.f, 0.f, 0.f);                            \
    float sp = 0.0f;                                                          \
    int pwi = __float_as_int(pw);                                             \
    int j = 0;                                                                \
    for (; j + 8 <= m; j += 8) {                                              \
        int c0 = RL_I(ec, j + 0), c1 = RL_I(ec, j + 1);                       \
        int c2 = RL_I(ec, j + 2), c3 = RL_I(ec, j + 3);                       \
        int c4 = RL_I(ec, j + 4), c5 = RL_I(ec, j + 5);                       \
        int c6 = RL_I(ec, j + 6), c7 = RL_I(ec, j + 7);                       \
        float p0 = __int_as_float(RL_I(pwi, j + 0));                          \
        float p1 = __int_as_float(RL_I(pwi, j + 1));                          \
        float p2 = __int_as_float(RL_I(pwi, j + 2));                          \
        float p3 = __int_as_float(RL_I(pwi, j + 3));                          \
        float p4 = __int_as_float(RL_I(pwi, j + 4));                          \
        float p5 = __int_as_float(RL_I(pwi, j + 5));                          \
        float p6 = __int_as_float(RL_I(pwi, j + 6));                          \
        float p7 = __int_as_float(RL_I(pwi, j + 7));                          \
        half4 v0 = *(const half4*)(xi + (size_t)c0 * BF + idx);               \
        half4 v1 = *(const half4*)(xi + (size_t)c1 * BF + idx);               \
        half4 v2 = *(const half4*)(xi + (size_t)c2 * BF + idx);               \
        half4 v3 = *(const half4*)(xi + (size_t)c3 * BF + idx);               \
        half4 v4 = *(const half4*)(xi + (size_t)c4 * BF + idx);               \
        half4 v5 = *(const half4*)(xi + (size_t)c5 * BF + idx);               \
        half4 v6 = *(const half4*)(xi + (size_t)c6 * BF + idx);               \
        half4 v7 = *(const half4*)(xi + (size_t)c7 * BF + idx);               \
        acc.x  += p0 * (float)v0[0]; acc.y  += p0 * (float)v0[1];             \
        acc.z  += p0 * (float)v0[2]; acc.w  += p0 * (float)v0[3];             \
        accB.x += p1 * (float)v1[0]; accB.y += p1 * (float)v1[1];             \
        accB.z += p1 * (float)v1[2]; accB.w += p1 * (float)v1[3];             \
        acc.x  += p2 * (float)v2[0]; acc.y  += p2 * (float)v2[1];             \
        acc.z  += p2 * (float)v2[2]; acc.w  += p2 * (float)v2[3];             \
        accB.x += p3 * (float)v3[0]; accB.y += p3 * (float)v3[1];             \
        accB.z += p3 * (float)v3[2]; accB.w += p3 * (float)v3[3];             \
        acc.x  += p4 * (float)v4[0]; acc.y  += p4 * (float)v4[1];             \
        acc.z  += p4 * (float)v4[2]; acc.w  += p4 * (float)v4[3];             \
        accB.x += p5 * (float)v5[0]; accB.y += p5 * (float)v5[1];             \
        accB.z += p5 * (float)v5[2]; accB.w += p5 * (float)v5[3];             \
        acc.x  += p6 * (float)v6[0]; acc.y  += p6 * (float)v6[1];             \
        acc.z  += p6 * (float)v6[2]; acc.w  += p6 * (float)v6[3];             \
        accB.x += p7 * (float)v7[0]; accB.y += p7 * (float)v7[1];             \
        accB.z += p7 * (float)v7[2]; accB.w += p7 * (float)v7[3];             \
        sp += p0 + p1 + p2 + p3 + p4 + p5 + p6 + p7;                          \
    }                                                                         \
    if (j + 4 <= m) {                                                         \
        int c0 = RL_I(ec, j + 0), c1 = RL_I(ec, j + 1);                       \
        int c2 = RL_I(ec, j + 2), c3 = RL_I(ec, j + 3);                       \
        float p0 = __int_as_float(RL_I(pwi, j + 0));                          \
        float p1 = __int_as_float(RL_I(pwi, j + 1));                          \
        float p2 = __int_as_float(RL_I(pwi, j + 2));                          \
        float p3 = __int_as_float(RL_I(pwi, j + 3));                          \
        half4 v0 = *(const half4*)(xi + (size_t)c0 * BF + idx);               \
        half4 v1 = *(const half4*)(xi + (size_t)c1 * BF + idx);               \
        half4 v2 = *(const half4*)(xi + (size_t)c2 * BF + idx);               \
        half4 v3 = *(const half4*)(xi + (size_t)c3 * BF + idx);               \
        acc.x  += p0 * (float)v0[0]; acc.y  += p0 * (float)v0[1];             \
        acc.z  += p0 * (float)v0[2]; acc.w  += p0 * (float)v0[3];             \
        accB.x += p1 * (float)v1[0]; accB.y += p1 * (float)v1[1];             \
        accB.z += p1 * (float)v1[2]; accB.w += p1 * (float)v1[3];             \
        acc.x  += p2 * (float)v2[0]; acc.y  += p2 * (float)v2[1];             \
        acc.z  += p2 * (float)v2[2]; acc.w  += p2 * (float)v2[3];             \
        accB.x += p3 * (float)v3[0]; accB.y += p3 * (float)v3[1];             \
        accB.z += p3 * (float)v3[2]; accB.w += p3 * (float)v3[3];             \
        sp += p0 + p1 + p2 + p3;                                              \
        j += 4;                                                               \
    }                                                                         \
    for (; j < m; ++j) {                                                      \
        int   c = RL_I(ec, j);                                                \
        float p = __int_as_float(RL_I(pwi, j));                               \
        NB_ONE(c, p)                                                          \
    }                                                                         \
    acc.x += accB.x; acc.y += accB.y; acc.z += accB.z; acc.w += accB.w;

// ========== gather -> fp16 ag (tier B): one wave per row ====================
__global__ __launch_bounds__(256) void k_gather_s(const int* __restrict__ cnt,
                                                  const uint2* __restrict__ slots,
                                                  const uint4* __restrict__ spill,
                                                  const _Float16* __restrict__ xi,
                                                  const float* __restrict__ dinv,
                                                  _Float16* __restrict__ ag,
                                                  float* __restrict__ s) {
    int r    = (int)(((size_t)blockIdx.x * 256 + threadIdx.x) >> 6);
    int lane = threadIdx.x & 63;
    if (r >= N_NODES) return;

    int cn = cnt[r];
    int m  = (cn < CAP) ? cn : CAP;
    int idx = lane * 4;

    int   ec = 0;
    float pw = 0.0f;
    if (lane < m) {
        uint2 en = slots[(size_t)r * CAP + lane];
        ec = (int)en.x;
        pw = __uint_as_float(en.y) * dinv[ec];
    }

    float dinvr = dinv[r];
    float nm0   = dinvr * dinvr;
    half4 hv    = *(const half4*)(xi + (size_t)r * BF + idx);

    NB_BODY

    if (cn > CAP) {
        int ns = cnt[N_NODES]; if (ns > SPILL_CAP) ns = SPILL_CAP;
        for (int i = 0; i < ns; ++i) {
            uint4 e = spill[i];
            if ((int)e.x == r) {
                int c = (int)e.y;
                float p = __uint_as_float(e.z) * dinv[c];
                NB_ONE(c, p)
            }
        }
    }

    half4 ho;
    ho[0] = (_Float16)(dinvr * acc.x + nm0 * (float)hv[0]);
    ho[1] = (_Float16)(dinvr * acc.y + nm0 * (float)hv[1]);
    ho[2] = (_Float16)(dinvr * acc.z + nm0 * (float)hv[2]);
    ho[3] = (_Float16)(dinvr * acc.w + nm0 * (float)hv[3]);
    *(half4*)(ag + (size_t)r * BF + idx) = ho;
    if (lane == 0) s[r] = dinvr * sp + nm0;
}

// ========== gather -> fp32 out (tier A, no ag buffer) =======================
__global__ __launch_bounds__(256) void k_gather_sf(const int* __restrict__ cnt,
                                                   const uint2* __restrict__ slots,
                                                   const uint4* __restrict__ spill,
                                                   const _Float16* __restrict__ xi,
                                                   const float* __restrict__ dinv,
                                                   float* __restrict__ out,
                                                   float* __restrict__ s) {
    int r    = (int)(((size_t)blockIdx.x * 256 + threadIdx.x) >> 6);
    int lane = threadIdx.x & 63;
    if (r >= N_NODES) return;

    int cn = cnt[r];
    int m  = (cn < CAP) ? cn : CAP;
    int idx = lane * 4;
    int b = idx >> 7;
    int f = idx & 127;

    int   ec = 0;
    float pw = 0.0f;
    if (lane < m) {
        uint2 en = slots[(size_t)r * CAP + lane];
        ec = (int)en.x;
        pw = __uint_as_float(en.y) * dinv[ec];
    }

    float dinvr = dinv[r];
    float nm0   = dinvr * dinvr;
    half4 hv    = *(const half4*)(xi + (size_t)r * BF + idx);

    NB_BODY

    if (cn > CAP) {
        int ns = cnt[N_NODES]; if (ns > SPILL_CAP) ns = SPILL_CAP;
        for (int i = 0; i < ns; ++i) {
            uint4 e = spill[i];
            if ((int)e.x == r) {
                int c = (int)e.y;
                float p = __uint_as_float(e.z) * dinv[c];
                NB_ONE(c, p)
            }
        }
    }

    float4 res = make_float4(dinvr * acc.x + nm0 * (float)hv[0],
                             dinvr * acc.y + nm0 * (float)hv[1],
                             dinvr * acc.z + nm0 * (float)hv[2],
                             dinvr * acc.w + nm0 * (float)hv[3]);
    *(float4*)(out + (size_t)b * NF + (size_t)r * F + f) = res;
    if (lane == 0) s[r] = dinvr * sp + nm0;
}

// ========== atomic fallback pieces (tiny ws) ================================
__global__ void k_deg(const int* __restrict__ ei, const float* __restrict__ attr,
                      float* __restrict__ deg) {
    int e = blockIdx.x * 256 + threadIdx.x;
    if (e < N_EDGES) atomicAdd(&deg[ei[e]], attr[e]);
}
__global__ void k_dinv(float* __restrict__ deg) {
    int n = blockIdx.x * 256 + threadIdx.x;
    if (n < N_NODES) deg[n] = rsqrtf(deg[n] + 1.0f);
}
__global__ __launch_bounds__(256) void k_edge(const int* __restrict__ ei,
                                              const float* __restrict__ attr,
                                              const float* __restrict__ dinv,
                                              const float* __restrict__ x,
                                              float* __restrict__ out,
                                              float* __restrict__ s) {
    int e    = (int)(((size_t)blockIdx.x * 256 + threadIdx.x) >> 6);
    int lane = threadIdx.x & 63;
    if (e >= N_EDGES) return;
    int r = ei[e];
    int c = ei[N_EDGES + e];
    float norm = dinv[r] * attr[e] * dinv[c];
    if (lane == 0) atomicAdd(&s[r], norm);
    int idx = lane * 4;
    int b = idx >> 7;
    int f = idx & 127;
    float4 v = *(const float4*)(x + (size_t)b * NF + (size_t)c * F + f);
    float* dst = out + (size_t)b * NF + (size_t)r * F + f;
    atomicAdd(dst + 0, norm * v.x);
    atomicAdd(dst + 1, norm * v.y);
    atomicAdd(dst + 2, norm * v.z);
    atomicAdd(dst + 3, norm * v.w);
}
__global__ void k_self(const float* __restrict__ x, const float* __restrict__ dinv,
                       float* __restrict__ out) {
    int i = blockIdx.x * 256 + threadIdx.x;
    if (i >= 2 * NF / 4) return;
    size_t base = (size_t)i * 4;
    int b = (base >= (size_t)NF) ? 1 : 0;
    size_t rem = base - (size_t)b * NF;
    int n = (int)(rem >> 7);
    float dn = dinv[n]; float sc = dn * dn;
    float4 v = *(const float4*)(x + base);
    float4* op = (float4*)(out + base);
    float4 o = *op;
    o.x += sc * v.x; o.y += sc * v.y; o.z += sc * v.z; o.w += sc * v.w;
    *op = o;
}
__global__ void k_sfix(const float* __restrict__ dinv, float* __restrict__ s) {
    int n = blockIdx.x * 256 + threadIdx.x;
    if (n < N_NODES) { float dn = dinv[n]; s[n] += dn * dn; }
}

// ========== MFMA GEMM, A direct from fp16 ag (tier B) =======================
__global__ __launch_bounds__(256) void k_gemm2(const _Float16* __restrict__ ag,
                                               const float* __restrict__ W,
                                               const float* __restrict__ bias,
                                               const float* __restrict__ s,
                                               float* __restrict__ out) {
    __shared__ _Float16 sW[128 * 136];
    const int tid = threadIdx.x;
    const int b   = blockIdx.y;
    const int n0  = blockIdx.x * 64;
    float* ob = out + (size_t)b * NF;

    for (int i = 0; i < 16; ++i) {
        int idx = (i * 256 + tid) * 4;
        int o = idx >> 7, k = idx & 127;
        float4 w = *(const float4*)(W + idx);
        half4 h;
        h[0] = (_Float16)w.x; h[1] = (_Float16)w.y;
        h[2] = (_Float16)w.z; h[3] = (_Float16)w.w;
        *(half4*)&sW[o * 136 + k] = h;
    }
    __syncthreads();

    const int wave = tid >> 6, lane = tid & 63;
    const int ln = lane & 15, quad = lane >> 4;
    const int nw = wave * 16;
    if (n0 + nw >= N_NODES) return;        // N_NODES % 16 == 0

    const _Float16* arow = ag + (size_t)(n0 + nw + ln) * BF + b * F;

    floatx4 acc[8];
    for (int ot = 0; ot < 8; ++ot) acc[ot] = (floatx4){0.f, 0.f, 0.f, 0.f};

    for (int k0 = 0; k0 < 4; ++k0) {
        half8 a = *(const half8*)(arow + k0 * 32 + quad * 8);
        for (int ot = 0; ot < 8; ++ot) {
            half8 bf = *(const half8*)&sW[(ot * 16 + ln) * 136 + k0 * 32 + quad * 8];
            acc[ot] = __builtin_amdgcn_mfma_f32_16x16x32_f16(a, bf, acc[ot], 0, 0, 0);
        }
    }

    float sv[4];
    for (int rg = 0; rg < 4; ++rg) sv[rg] = s[n0 + nw + quad * 4 + rg];
    for (int ot = 0; ot < 8; ++ot) {
        int o = ot * 16 + ln;
        float bo = bias[o];
        for (int rg = 0; rg < 4; ++rg) {
            int n = n0 + nw + quad * 4 + rg;
            float v = acc[ot][rg] + sv[rg] * bo;
            ob[(size_t)n * F + o] = fmaxf(v, 0.0f);
        }
    }
}

// ========== MFMA GEMM, A from fp32 out via LDS (tier A / fallback) ==========
__global__ __launch_bounds__(256) void k_gemm1(const float* __restrict__ W,
                                               const float* __restrict__ bias,
                                               const float* __restrict__ s,
                                               float* __restrict__ out) {
    __shared__ _Float16 sW[128 * 136];
    __shared__ _Float16 sA[64 * 136];
    const int tid = threadIdx.x;
    const int b   = blockIdx.y;
    const int n0  = blockIdx.x * 64;
    float* ob = out + (size_t)b * NF;

    for (int i = 0; i < 16; ++i) {
        int idx = (i * 256 + tid) * 4;
        int o = idx >> 7, k = idx & 127;
        float4 w = *(const float4*)(W + idx);
        half4 h;
        h[0] = (_Float16)w.x; h[1] = (_Float16)w.y;
        h[2] = (_Float16)w.z; h[3] = (_Float16)w.w;
        *(half4*)&sW[o * 136 + k] = h;
    }
    for (int i = 0; i < 8; ++i) {
        int idx = (i * 256 + tid) * 4;
        int nl = idx >> 7, k = idx & 127;
        int n = n0 + nl;
        half4 h = {(_Float16)0.f, (_Float16)0.f, (_Float16)0.f, (_Float16)0.f};
        if (n < N_NODES) {
            float4 v = *(const float4*)(ob + (size_t)n * F + k);
            h[0] = (_Float16)v.x; h[1] = (_Float16)v.y;
            h[2] = (_Float16)v.z; h[3] = (_Float16)v.w;
        }
        *(half4*)&sA[nl * 136 + k] = h;
    }
    __syncthreads();

    const int wave = tid >> 6, lane = tid & 63;
    const int ln = lane & 15, quad = lane >> 4;
    const int nw = wave * 16;
    if (n0 + nw >= N_NODES) return;

    floatx4 acc[8];
    for (int ot = 0; ot < 8; ++ot) acc[ot] = (floatx4){0.f, 0.f, 0.f, 0.f};

    for (int k0 = 0; k0 < 4; ++k0) {
        half8 a = *(const half8*)&sA[(nw + ln) * 136 + k0 * 32 + quad * 8];
        for (int ot = 0; ot < 8; ++ot) {
            half8 bf = *(const half8*)&sW[(ot * 16 + ln) * 136 + k0 * 32 + quad * 8];
            acc[ot] = __builtin_amdgcn_mfma_f32_16x16x32_f16(a, bf, acc[ot], 0, 0, 0);
        }
    }

    float sv[4];
    for (int rg = 0; rg < 4; ++rg) sv[rg] = s[n0 + nw + quad * 4 + rg];
    for (int ot = 0; ot < 8; ++ot) {
        int o = ot * 16 + ln;
        float bo = bias[o];
        for (int rg = 0; rg < 4; ++rg) {
            int n = n0 + nw + quad * 4 + rg;
            float v = acc[ot][rg] + sv[rg] * bo;
            ob[(size_t)n * F + o] = fmaxf(v, 0.0f);
        }
    }
}

extern "C" void kernel_launch(void* const* d_in, const int* in_sizes, int n_in,
                              void* d_out, int out_size, void* d_ws, size_t ws_size,
                              hipStream_t stream) {
    const float* x    = (const float*)d_in[0];
    const int*   ei   = (const int*)d_in[1];
    const float* attr = (const float*)d_in[2];
    const float* W    = (const float*)d_in[3];
    const float* bias = (const float*)d_in[4];
    float* out = (float*)d_out;

    // ws layout: cnt[N+1] | dinv[N] | s[N] | pad16 | spill[SPILL_CAP]*16B |
    //            slots[N*CAP]*8B | xi[2NF]*2B | ag[2NF]*2B (tier B only)
    int*   cnt  = (int*)d_ws;
    float* dinv = (float*)(cnt + N_NODES + 1);
    float* s    = dinv + N_NODES;
    size_t spill_off = ((size_t)((char*)(s + N_NODES) - (char*)d_ws) + 15) & ~(size_t)15;
    uint4* spill = (uint4*)((char*)d_ws + spill_off);
    size_t slots_off = spill_off + (size_t)SPILL_CAP * 16;
    uint2* slots = (uint2*)((char*)d_ws + slots_off);
    size_t xi_off = slots_off + (size_t)N_NODES * CAP * 8;
    _Float16* xi = (_Float16*)((char*)d_ws + xi_off);
    size_t ag_off = xi_off + (size_t)2 * NF * 2;
    _Float16* ag = (_Float16*)((char*)d_ws + ag_off);

    size_t need_A = ag_off;                        // slotted, gather -> fp32 out
    size_t need_B = ag_off + (size_t)2 * NF * 2;   // + fp16 ag

    dim3 gg((N_NODES + 63) / 64, 2);
    size_t rthreads = (size_t)N_NODES * 64;
    unsigned rblocks = (unsigned)((rthreads + 255) / 256);

    if (ws_size >= need_A) {
        hipMemsetAsync(cnt, 0, (N_NODES + 1) * sizeof(int), stream);
        k_build<<<PRE_BLOCKS, 256, 0, stream>>>(ei, attr, x, cnt, spill, slots, xi);
        k_deg_s<<<rblocks, 256, 0, stream>>>(cnt, slots, spill, dinv);
        if (ws_size >= need_B) {
            k_gather_s<<<rblocks, 256, 0, stream>>>(cnt, slots, spill, xi, dinv, ag, s);
            k_gemm2<<<gg, 256, 0, stream>>>(ag, W, bias, s, out);
        } else {
            k_gather_sf<<<rblocks, 256, 0, stream>>>(cnt, slots, spill, xi, dinv, out, s);
            k_gemm1<<<gg, 256, 0, stream>>>(W, bias, s, out);
        }
    } else {
        // atomic fallback: needs dinv[N]+s[N] only
        hipMemsetAsync(dinv, 0, N_NODES * sizeof(float), stream);
        hipMemsetAsync(s, 0, N_NODES * sizeof(float), stream);
        hipMemsetAsync(out, 0, (size_t)2 * NF * sizeof(float), stream);
        k_deg<<<(N_EDGES + 255) / 256, 256, 0, stream>>>(ei, attr, dinv);
        k_dinv<<<(N_NODES + 255) / 256, 256, 0, stream>>>(dinv);
        size_t edge_threads = (size_t)N_EDGES * 64;
        k_edge<<<(unsigned)((edge_threads + 255) / 256), 256, 0, stream>>>(
            ei, attr, dinv, x, out, s);
        k_self<<<(2 * NF / 4 + 255) / 256, 256, 0, stream>>>(x, dinv, out);
        k_sfix<<<(N_NODES + 255) / 256, 256, 0, stream>>>(dinv, s);
        k_gemm1<<<gg, 256, 0, stream>>>(W, bias, s, out);
    }
}